// Round 13
// baseline (1173.050 us; speedup 1.0000x reference)
//
#include <hip/hip_runtime.h>

#define H    51
#define BB   2048
#define TSEQ 1024
#define NB   4          // 4 batches/block -> 512 blocks -> 2 co-resident blocks/CU
#define NT   1024       // 16 waves; 2 blocks x 16 = 32 waves/CU (max occupancy)
#define KP   72         // f16 h-row stride (144B, 16B-aligned)
#define XSL  51         // x (layer-1 input) lives in k-slot 51 of the h1 buffer

typedef __attribute__((ext_vector_type(8))) _Float16 half8;
typedef __attribute__((ext_vector_type(4))) float f32x4;

// v_rcp_f32 (1 ulp) via compiler-known intrinsic (proven r3)
__device__ __forceinline__ float rcp_(float x) { return __builtin_amdgcn_rcpf(x); }

__device__ __forceinline__ float sigm(float x) { return rcp_(1.0f + __expf(-x)); }
__device__ __forceinline__ float tanh_(float x) { return fmaf(-2.0f, rcp_(__expf(2.0f * x) + 1.0f), 1.0f); }

#define MFMA(a, b, c) __builtin_amdgcn_mfma_f32_16x16x32_f16((a), (b), (c), 0, 0, 0)

// lgkmcnt-only barrier (proven r3/r4): LDS ordering without draining vmcnt.
#define BARR() do { asm volatile("s_waitcnt lgkmcnt(0)" ::: "memory");            \
                    __builtin_amdgcn_s_barrier(); } while (0)

struct SM {
    alignas(16) _Float16 h1[2][8][KP];    // parity-buffered h1 (f16); k=51 carries x
    alignas(16) _Float16 h2[2][8][KP];    // rows NB..7 dead (bounded garbage, never consumed)
};

// A-frags (f16) for tile T of gate-stacked [3H][H] matrix, 4-padded rows:
// padded row 16T+n -> element j=4T+(n>>2), gate slot c=n&3.
// nslot selects which slot carries the n-gate row (2 = normal; 3 = moved).
__device__ __forceinline__ void loadA(const float* __restrict__ src, int T, int n, int q,
                                      half8* a, int nslot) {
    const int jt = 4 * T + (n >> 2);
    const int c  = n & 3;
    const int g  = (c == 0) ? 0 : (c == 1) ? 1 : (c == nslot) ? 2 : -1;
    const bool rv = (g >= 0) && (jt < H);
#pragma unroll
    for (int kb = 0; kb < 2; ++kb) {
        half8 hv;
#pragma unroll
        for (int jj = 0; jj < 8; ++jj) {
            const int k = kb * 32 + q * 8 + jj;
            const float v = (rv && k < H) ? src[(g * H + jt) * H + k] : 0.f;
            hv[jj] = (_Float16)v;     // RNE
        }
        a[kb] = hv;
    }
}

// L1 A-frag: whh1 rows for k<51 PLUS wih1 column at k==XSL (x rides the MFMA):
// slot c0: [whh1_r | w1r@51], c1: [whh1_z | w1z@51], c2: [whh1_n | 0@51],
// c3: [0 | w1n@51]  ->  a.w accumulates bih1n + w1n*x (i-side of n gate).
__device__ __forceinline__ void loadA1(const float* __restrict__ whh1,
                                       const float* __restrict__ wih1,
                                       int T, int n, int q, half8* a) {
    const int jt = 4 * T + (n >> 2);
    const int c  = n & 3;
    const bool jok = (jt < H);
#pragma unroll
    for (int kb = 0; kb < 2; ++kb) {
        half8 hv;
#pragma unroll
        for (int jj = 0; jj < 8; ++jj) {
            const int k = kb * 32 + q * 8 + jj;
            float v = 0.f;
            if (jok) {
                if (c < 2) {
                    if (k < H)        v = whh1[(c * H + jt) * H + k];
                    else if (k == XSL) v = wih1[c * H + jt];
                } else if (c == 2) {
                    if (k < H)        v = whh1[(2 * H + jt) * H + k];
                } else {              // c == 3: x-only row for the n gate
                    if (k == XSL)     v = wih1[2 * H + jt];
                }
            }
            hv[jj] = (_Float16)v;
        }
        a[kb] = hv;
    }
}

// chained 2-MFMA matvec over K=64, bias folded into accumulator init
__device__ __forceinline__ f32x4 dot2(const half8* a, half8 b0, half8 b1, f32x4 init) {
    f32x4 acc = init;
    acc = MFMA(a[0], b0, acc);
    acc = MFMA(a[1], b1, acc);
    return acc;
}

__global__ __launch_bounds__(NT, 1) void gru_persist(
    const float* __restrict__ inp, const int* __restrict__ fut,
    const float* __restrict__ wih1, const float* __restrict__ whh1,
    const float* __restrict__ bih1, const float* __restrict__ bhh1,
    const float* __restrict__ wih2, const float* __restrict__ whh2,
    const float* __restrict__ bih2, const float* __restrict__ bhh2,
    const float* __restrict__ wlin, const float* __restrict__ blin,
    float* __restrict__ out)
{
    __shared__ SM sm;
    const int t = threadIdx.x, bg = blockIdx.x;
    const int w = t >> 6, lane = t & 63;
    const int n = lane & 15, q = lane >> 4;
    const int nb = n & 7;                      // broadcast row (n and n+8 share)
    const bool hiL = (n >= 8);                 // lane-pack: hi half runs L1 gates
    // SIMD balance (proven r4): tile 12 on wave 15 -> light waves {12,13,14,15}
    // land on distinct SIMDs; every SIMD carries 3 matvec + 1 light wave.
    const bool doM = (w < 12) || (w == 15);
    const int  T   = (w == 15) ? 12 : (doM ? w : 0);
    const int  j   = 4 * T + q;
    const bool jv  = doM && (j < H) && (n < NB);   // lo-lane write gate
    const bool jw  = doM && (j < H);               // any-lane write gate
    const int  jcl = (j < H) ? j : 0;

    // ---- A-fragments: 6 half8 = 24 VGPRs (wih2's n-row in slot 3) ----
    half8 a1[2], a2[2], a3[2];
    loadA1(whh1, wih1, T, n, q, a1);
    loadA(whh2, T, n, q, a2, 2);
    loadA(wih2, T, n, q, a3, 3);

    // ---- per-lane constants; biases folded into f32x4 accumulator inits ----
    // L1: .x/.y = both r/z biases, .z = bhh1n, .w = bih1n (x-term lands via MFMA)
    const f32x4 b1v  = {bhh1[jcl] + bih1[jcl], bhh1[H + jcl] + bih1[H + jcl],
                        bhh1[2 * H + jcl], bih1[2 * H + jcl]};
    // L2 combined chain (whh2 then wih2): proven r4
    const f32x4 b2c2 = {bhh2[jcl] + bih2[jcl], bhh2[H + jcl] + bih2[H + jcl],
                        bhh2[2 * H + jcl], bih2[2 * H + jcl]};
    // future-loop split inits (phases separated by a barrier there)
    const f32x4 ib2v = {bhh2[jcl], bhh2[H + jcl], bhh2[2 * H + jcl], 0.f};
    const f32x4 ic2v = {bih2[jcl], bih2[H + jcl], 0.f, bih2[2 * H + jcl]};
    const float blin_r = blin[0];

    // ---- reducer constants (wave 14): lane = n8*8+c8 covers batch x k-chunk ----
    const int n8 = lane >> 3, c8 = lane & 7;
    float wlv[8];
#pragma unroll
    for (int jj = 0; jj < 8; ++jj) {
        const int ix = c8 * 8 + jj;
        wlv[jj] = (ix < H) ? wlin[ix] : 0.f;
    }

    // ---- LDS init (zeros; x/o slots written after the fence) ----
    for (int i = t; i < 2 * 8 * KP; i += NT) { ((short*)sm.h1)[i] = 0; ((short*)sm.h2)[i] = 0; }
    __syncthreads();

    // ---- x staging: wave 13, lanes 0..NB-1 write x(i+1) -> h1[PAR^1][bs][XSL] ----
    const bool doX = (w == 13) && (lane < NB);
    const int  bs  = lane;
    const float* xrow = inp + (size_t)(bg * NB + (doX ? bs : 0)) * TSEQ;
    float4 cn = make_float4(0.f, 0.f, 0.f, 0.f);
    float4 nx = make_float4(0.f, 0.f, 0.f, 0.f);
    if (doX) {
        cn = *(const float4*)xrow;                 // x[0..3]
        nx = *(const float4*)(xrow + 4);           // x[4..7]
        sm.h1[0][bs][XSL] = (_Float16)cn.x;        // x(0)
    }

    // lane-packed hidden state: lanes n<8 hold h2o, lanes n>=8 hold h1o
    float hoM = 0.f;
    const int TT = TSEQ + fut[0];
    float* outp = out + (size_t)(bg * NB) * (size_t)TT;
    __syncthreads();

// reducer: o = wlin . h2[PARI] + b via ONE ds_read_b128; writes gated n8 < NB
// (rows NB..7 of h2 are dead-garbage -> their v is discarded by the gate)
#define REDH(PARI, TIDX, DOWR, WRP)                                               \
{                                                                                 \
    const half8 hv = *(const half8*)&sm.h2[PARI][n8][c8 * 8];                     \
    float v = 0.f;                                                                \
    _Pragma("unroll")                                                             \
    for (int jj = 0; jj < 8; ++jj) v = fmaf((float)hv[jj], wlv[jj], v);           \
    v += __shfl_xor(v, 1);                                                        \
    v += __shfl_xor(v, 2);                                                        \
    v += __shfl_xor(v, 4);                                                        \
    if (c8 == 0 && n8 < NB) {                                                     \
        const float o_ = v + blin_r;                                              \
        if (DOWR) sm.h1[WRP][n8][XSL] = (_Float16)o_;                             \
        outp[(size_t)n8 * TT + (TIDX)] = o_;                                      \
    }                                                                             \
}

// Lane-packed step (proven r11): lanes n<8 run the L2 gate chain, lanes n>=8
// run L1's (MFMA outputs are lane-duplicated via broadcast B); hi lanes write
// h1[n-8][j] directly, lo lanes write h2[n][j]. Rows NB..7 carry bounded
// garbage (all consumers gated n < NB).
#define STEP(IV, PAR, XC, DOL2, DORED)                                            \
{                                                                                 \
    const int i_ = (IV);                                                          \
    if (doM) {                                                                    \
        const half8 b10 = *(const half8*)&sm.h1[PAR][nb][q * 8];                  \
        const half8 b11 = *(const half8*)&sm.h1[PAR][nb][32 + q * 8];             \
        if (DOL2) {                                                               \
            const half8 b20 = *(const half8*)&sm.h2[PAR][nb][q * 8];              \
            const half8 b21 = *(const half8*)&sm.h2[PAR][nb][32 + q * 8];         \
            f32x4 g = dot2(a2, b20, b21, b2c2);                                   \
            g = dot2(a3, b10, b11, g);                                            \
            const f32x4 a = dot2(a1, b10, b11, b1v);   /* x-term via k=51 */      \
            const float rA = hiL ? a.x : g.x;                                     \
            const float zA = hiL ? a.y : g.y;                                     \
            const float nh = hiL ? a.z : g.z;                                     \
            const float ni = hiL ? a.w : g.w;                                     \
            const float gr = sigm(rA);                                            \
            const float gz = sigm(zA);                                            \
            const float gn = tanh_(fmaf(gr, nh, ni));                             \
            const float hn = gn + gz * (hoM - gn);                                \
            hoM = hn;                                                             \
            if (jw) {                                                             \
                if (hiL) sm.h1[(PAR) ^ 1][nb][j] = (_Float16)hn;                  \
                else     sm.h2[(PAR) ^ 1][n][j]  = (_Float16)hn;                  \
            }                                                                     \
        } else {                                   /* step 0: L1 only */          \
            const f32x4 a = dot2(a1, b10, b11, b1v);                              \
            const float gr = sigm(a.x);                                           \
            const float gz = sigm(a.y);                                           \
            const float gn = tanh_(fmaf(gr, a.z, a.w));                           \
            const float hn = gn - gz * gn;         /* h1o = 0 */                  \
            if (hiL) {                                                            \
                hoM = hn;                                                         \
                if (jw) sm.h1[(PAR) ^ 1][nb][j] = (_Float16)hn;                   \
            }                                                                     \
        }                                                                         \
    } else if (w == 14) {                                                         \
        if (DORED) REDH(PAR, i_ - 2, false, 0)                                    \
    } else if (doX && (i_ + 1) < TSEQ) {                                          \
        if ((XC) == 0) cn = nx;                                                   \
        const float xv_ = ((XC) == 0) ? cn.x : ((XC) == 1) ? cn.y                 \
                        : ((XC) == 2) ? cn.z : cn.w;                              \
        sm.h1[(PAR) ^ 1][bs][XSL] = (_Float16)xv_;                                \
        if ((XC) == 0 && (i_ + 5) < TSEQ) nx = *(const float4*)(xrow + i_ + 5);   \
    }                                                                             \
    BARR();                                                                       \
}

    // ========== MAIN LOOP: 1 barrier/step, unroll-4 (static x-component) ==========
    STEP(0, 0, 1, false, false)
    STEP(1, 1, 2, true,  false)
    for (int i = 2; i < TSEQ - 2; i += 4) {
        STEP(i,     0, 3, true, true)
        STEP(i + 1, 1, 0, true, true)
        STEP(i + 2, 0, 1, true, true)
        STEP(i + 3, 1, 2, true, true)
    }
    STEP(TSEQ - 2, 0, 3, true, true)
    STEP(TSEQ - 1, 1, 0, true, true)

    // ---- unpack lane-packed state for epilogue/future loop (one shfl, once) ----
    float h1o = __shfl_xor(hoM, 8);
    float h2o = hoM;

    // ========== EPILOGUE: h2(TSEQ-1), flush o(TSEQ-2) and o(TSEQ-1) ==========
    // state: h1(TSEQ-1) in h1[0], h2(TSEQ-2) in h2[0]
    if (doM) {
        const half8 b10 = *(const half8*)&sm.h1[0][nb][q * 8];
        const half8 b11 = *(const half8*)&sm.h1[0][nb][32 + q * 8];
        const half8 b20 = *(const half8*)&sm.h2[0][nb][q * 8];
        const half8 b21 = *(const half8*)&sm.h2[0][nb][32 + q * 8];
        f32x4 g = dot2(a2, b20, b21, b2c2);
        g = dot2(a3, b10, b11, g);
        const float gr = sigm(g.x);
        const float gz = sigm(g.y);
        const float gn = tanh_(fmaf(gr, g.z, g.w));
        const float hn = gn + gz * (h2o - gn);
        h2o = hn;
        if (jv) sm.h2[1][n][j] = (_Float16)hn;
    } else if (w == 14) {
        REDH(0, TSEQ - 2, false, 0)
    }
    BARR();
    if (w == 14) {
        REDH(1, TSEQ - 1, true, 0)      // o(TSEQ-1) -> out + h1[0] x-slot (future x)
    }
    BARR();

    // ========== FUTURE LOOP: serial feedback, 3 barriers/step ==========
    // L1 is IDENTICAL to the main loop (x = o rides slot 51 of h1).
    int fp1 = 0, fh2 = 1;    // h1(TSEQ-1)+o in h1[0], h2(TSEQ-1) in h2[1]
    for (int ts = TSEQ; ts < TT; ++ts) {
        float g2r, g2z, g2n;
        if (doM) {
            const half8 b10 = *(const half8*)&sm.h1[fp1][nb][q * 8];
            const half8 b11 = *(const half8*)&sm.h1[fp1][nb][32 + q * 8];
            const half8 b20 = *(const half8*)&sm.h2[fh2][nb][q * 8];
            const half8 b21 = *(const half8*)&sm.h2[fh2][nb][32 + q * 8];
            {
                const f32x4 g = dot2(a2, b20, b21, ib2v);
                g2r = g.x; g2z = g.y; g2n = g.z;
            }
            {
                const f32x4 a = dot2(a1, b10, b11, b1v);   // x-term via k=51
                const float gr = sigm(a.x);
                const float gz = sigm(a.y);
                const float gn = tanh_(fmaf(gr, a.z, a.w));
                const float hn = gn + gz * (h1o - gn);
                h1o = hn;
                if (jv) sm.h1[fp1 ^ 1][n][j] = (_Float16)hn;
            }
        }
        BARR();
        if (doM) {
            const half8 c0 = *(const half8*)&sm.h1[fp1 ^ 1][nb][q * 8];
            const half8 c1 = *(const half8*)&sm.h1[fp1 ^ 1][nb][32 + q * 8];
            const f32x4 gi = dot2(a3, c0, c1, ic2v);       // n-part lands in .w
            const float gr = sigm(gi.x + g2r);
            const float gz = sigm(gi.y + g2z);
            const float gn = tanh_(fmaf(gr, g2n, gi.w));
            const float hn = gn + gz * (h2o - gn);
            h2o = hn;
            if (jv) sm.h2[fh2 ^ 1][n][j] = (_Float16)hn;
        }
        BARR();
        if (w == 14) {
            REDH(fh2 ^ 1, ts, true, fp1 ^ 1)   // o(ts) -> out + next step's x-slot
        }
        BARR();
        fp1 ^= 1; fh2 ^= 1;
    }
}

extern "C" void kernel_launch(void* const* d_in, const int* in_sizes, int n_in,
                              void* d_out, int out_size, void* d_ws, size_t ws_size,
                              hipStream_t stream) {
    (void)in_sizes; (void)n_in; (void)d_ws; (void)ws_size; (void)out_size;
    gru_persist<<<BB / NB, NT, 0, stream>>>(
        (const float*)d_in[0], (const int*)d_in[1],
        (const float*)d_in[2], (const float*)d_in[3], (const float*)d_in[4], (const float*)d_in[5],
        (const float*)d_in[6], (const float*)d_in[7], (const float*)d_in[8], (const float*)d_in[9],
        (const float*)d_in[10], (const float*)d_in[11],
        (float*)d_out);
}

// Round 14
// 661.521 us; speedup vs baseline: 1.7733x; 1.7733x over previous
//
#include <hip/hip_runtime.h>

#define H    51
#define BB   2048
#define TSEQ 1024
#define NB   8
#define NT   1024       // 16 waves, 4/SIMD
#define KP   72         // f16 h-row stride (144B, 16B-aligned)
#define XSL  51         // x (layer-1 input) lives in k-slot 51 of the h1 buffer

typedef __attribute__((ext_vector_type(8))) _Float16 half8;
typedef __attribute__((ext_vector_type(4))) float f32x4;

// v_rcp_f32 (1 ulp) via compiler-known intrinsic (proven r3)
__device__ __forceinline__ float rcp_(float x) { return __builtin_amdgcn_rcpf(x); }

__device__ __forceinline__ float sigm(float x) { return rcp_(1.0f + __expf(-x)); }
__device__ __forceinline__ float tanh_(float x) { return fmaf(-2.0f, rcp_(__expf(2.0f * x) + 1.0f), 1.0f); }

#define MFMA(a, b, c) __builtin_amdgcn_mfma_f32_16x16x32_f16((a), (b), (c), 0, 0, 0)

// lgkmcnt-only barrier (proven r3/r4): LDS ordering without draining vmcnt.
#define BARR() do { asm volatile("s_waitcnt lgkmcnt(0)" ::: "memory");            \
                    __builtin_amdgcn_s_barrier(); } while (0)

struct SM {
    alignas(16) _Float16 h1[2][8][KP];    // parity-buffered h1 (f16); k=51 carries x
    alignas(16) _Float16 h2[2][8][KP];    // parity-buffered h2 (k>=51 stays 0)
};

// A-frags (f16) for tile T of gate-stacked [3H][H] matrix, 4-padded rows:
// padded row 16T+n -> element j=4T+(n>>2), gate slot c=n&3.
// nslot selects which slot carries the n-gate row (2 = normal; 3 = moved).
__device__ __forceinline__ void loadA(const float* __restrict__ src, int T, int n, int q,
                                      half8* a, int nslot) {
    const int jt = 4 * T + (n >> 2);
    const int c  = n & 3;
    const int g  = (c == 0) ? 0 : (c == 1) ? 1 : (c == nslot) ? 2 : -1;
    const bool rv = (g >= 0) && (jt < H);
#pragma unroll
    for (int kb = 0; kb < 2; ++kb) {
        half8 hv;
#pragma unroll
        for (int jj = 0; jj < 8; ++jj) {
            const int k = kb * 32 + q * 8 + jj;
            const float v = (rv && k < H) ? src[(g * H + jt) * H + k] : 0.f;
            hv[jj] = (_Float16)v;     // RNE
        }
        a[kb] = hv;
    }
}

// L1 A-frag: whh1 rows for k<51 PLUS wih1 column at k==XSL (x rides the MFMA):
// slot c0: [whh1_r | w1r@51], c1: [whh1_z | w1z@51], c2: [whh1_n | 0@51],
// c3: [0 | w1n@51]  ->  a.w accumulates bih1n + w1n*x (i-side of n gate).
__device__ __forceinline__ void loadA1(const float* __restrict__ whh1,
                                       const float* __restrict__ wih1,
                                       int T, int n, int q, half8* a) {
    const int jt = 4 * T + (n >> 2);
    const int c  = n & 3;
    const bool jok = (jt < H);
#pragma unroll
    for (int kb = 0; kb < 2; ++kb) {
        half8 hv;
#pragma unroll
        for (int jj = 0; jj < 8; ++jj) {
            const int k = kb * 32 + q * 8 + jj;
            float v = 0.f;
            if (jok) {
                if (c < 2) {
                    if (k < H)        v = whh1[(c * H + jt) * H + k];
                    else if (k == XSL) v = wih1[c * H + jt];
                } else if (c == 2) {
                    if (k < H)        v = whh1[(2 * H + jt) * H + k];
                } else {              // c == 3: x-only row for the n gate
                    if (k == XSL)     v = wih1[2 * H + jt];
                }
            }
            hv[jj] = (_Float16)v;
        }
        a[kb] = hv;
    }
}

// chained 2-MFMA matvec over K=64, bias folded into accumulator init
__device__ __forceinline__ f32x4 dot2(const half8* a, half8 b0, half8 b1, f32x4 init) {
    f32x4 acc = init;
    acc = MFMA(a[0], b0, acc);
    acc = MFMA(a[1], b1, acc);
    return acc;
}

__global__ __launch_bounds__(NT, 1) void gru_persist(
    const float* __restrict__ inp, const int* __restrict__ fut,
    const float* __restrict__ wih1, const float* __restrict__ whh1,
    const float* __restrict__ bih1, const float* __restrict__ bhh1,
    const float* __restrict__ wih2, const float* __restrict__ whh2,
    const float* __restrict__ bih2, const float* __restrict__ bhh2,
    const float* __restrict__ wlin, const float* __restrict__ blin,
    float* __restrict__ out)
{
    __shared__ SM sm;
    const int t = threadIdx.x, bg = blockIdx.x;
    const int w = t >> 6, lane = t & 63;
    const int n = lane & 15, q = lane >> 4;
    const int nb = n & 7;                      // broadcast row (n and n+8 share)
    const bool hiL = (n >= 8);                 // lane-pack: hi half runs L1 gates
    // SIMD balance (proven r4): tile 12 on wave 15 -> light waves {12,13,14,15}
    // land on distinct SIMDs; every SIMD carries 3 matvec + 1 light wave.
    const bool doM = (w < 12) || (w == 15);
    const int  T   = (w == 15) ? 12 : (doM ? w : 0);
    const int  j   = 4 * T + q;
    const bool jv  = doM && (j < H) && (n < NB);   // lo-lane write gate
    const bool jw  = doM && (j < H);               // any-lane write gate
    const int  jcl = (j < H) ? j : 0;

    // ---- A-fragments: 6 half8 = 24 VGPRs (wih2's n-row in slot 3) ----
    half8 a1[2], a2[2], a3[2];
    loadA1(whh1, wih1, T, n, q, a1);
    loadA(whh2, T, n, q, a2, 2);
    loadA(wih2, T, n, q, a3, 3);

    // ---- per-lane constants; biases folded into f32x4 accumulator inits ----
    // L1: .x/.y = both r/z biases, .z = bhh1n, .w = bih1n (x-term lands via MFMA)
    const f32x4 b1v  = {bhh1[jcl] + bih1[jcl], bhh1[H + jcl] + bih1[H + jcl],
                        bhh1[2 * H + jcl], bih1[2 * H + jcl]};
    // L2 split inits: two INDEPENDENT 2-MFMA chains (halves dependent-MFMA
    // depth on the step's critical path; r5 precedent for the summation split)
    const f32x4 ib2v = {bhh2[jcl], bhh2[H + jcl], bhh2[2 * H + jcl], 0.f};
    const f32x4 ic2v = {bih2[jcl], bih2[H + jcl], 0.f, bih2[2 * H + jcl]};
    const float blin_r = blin[0];

    // ---- reducer constants (wave 14): lane = n8*8+c8 covers batch x k-chunk ----
    const int n8 = lane >> 3, c8 = lane & 7;
    float wlv[8];
#pragma unroll
    for (int jj = 0; jj < 8; ++jj) {
        const int ix = c8 * 8 + jj;
        wlv[jj] = (ix < H) ? wlin[ix] : 0.f;
    }

    // ---- LDS init (zeros; x/o slots written after the fence) ----
    for (int i = t; i < 2 * 8 * KP; i += NT) { ((short*)sm.h1)[i] = 0; ((short*)sm.h2)[i] = 0; }
    __syncthreads();

    // ---- x staging: wave 13, lanes 0..7 write x(i+1) -> h1[PAR^1][bs][XSL] ----
    const bool doX = (w == 13) && (lane < 8);
    const int  bs  = lane;
    const float* xrow = inp + (size_t)(bg * NB + (doX ? bs : 0)) * TSEQ;
    float4 cn = make_float4(0.f, 0.f, 0.f, 0.f);
    float4 nx = make_float4(0.f, 0.f, 0.f, 0.f);
    if (doX) {
        cn = *(const float4*)xrow;                 // x[0..3]
        nx = *(const float4*)(xrow + 4);           // x[4..7]
        sm.h1[0][bs][XSL] = (_Float16)cn.x;        // x(0)
    }

    // lane-packed hidden state: lanes n<8 hold h2o, lanes n>=8 hold h1o
    float hoM = 0.f;
    const int TT = TSEQ + fut[0];
    float* outp = out + (size_t)(bg * NB) * (size_t)TT;
    __syncthreads();

// reducer: o = wlin . h2[PARI] + b via ONE ds_read_b128
#define REDH(PARI, TIDX, DOWR, WRP)                                               \
{                                                                                 \
    const half8 hv = *(const half8*)&sm.h2[PARI][n8][c8 * 8];                     \
    float v = 0.f;                                                                \
    _Pragma("unroll")                                                             \
    for (int jj = 0; jj < 8; ++jj) v = fmaf((float)hv[jj], wlv[jj], v);           \
    v += __shfl_xor(v, 1);                                                        \
    v += __shfl_xor(v, 2);                                                        \
    v += __shfl_xor(v, 4);                                                        \
    if (c8 == 0) {                                                                \
        const float o_ = v + blin_r;                                              \
        if (DOWR) sm.h1[WRP][n8][XSL] = (_Float16)o_;                             \
        outp[(size_t)n8 * TT + (TIDX)] = o_;                                      \
    }                                                                             \
}

// Lane-packed step (proven r11) with SPLIT L2 chains (this round): g and gi
// are independent 2-MFMA chains (a-chain independent too) -> MFMA critical
// depth 2 instead of 4; lo lanes select g+gi, hi lanes select a. Slot algebra:
// g.z = n_h (a2 slot2), gi.w = n_i (a3 slot3); g.w = gi.z = 0 (zero rows), so
// componentwise s = g+gi is exactly {r2, z2, n_h, n_i}.
#define STEP(IV, PAR, XC, DOL2, DORED)                                            \
{                                                                                 \
    const int i_ = (IV);                                                          \
    if (doM) {                                                                    \
        const half8 b10 = *(const half8*)&sm.h1[PAR][nb][q * 8];                  \
        const half8 b11 = *(const half8*)&sm.h1[PAR][nb][32 + q * 8];             \
        if (DOL2) {                                                               \
            const half8 b20 = *(const half8*)&sm.h2[PAR][nb][q * 8];              \
            const half8 b21 = *(const half8*)&sm.h2[PAR][nb][32 + q * 8];         \
            const f32x4 g  = dot2(a2, b20, b21, ib2v);                            \
            const f32x4 gi = dot2(a3, b10, b11, ic2v);                            \
            const f32x4 a  = dot2(a1, b10, b11, b1v);  /* x-term via k=51 */      \
            const f32x4 s  = g + gi;                                             \
            const float rA = hiL ? a.x : s.x;                                     \
            const float zA = hiL ? a.y : s.y;                                     \
            const float nh = hiL ? a.z : s.z;                                     \
            const float ni = hiL ? a.w : s.w;                                     \
            const float gr = sigm(rA);                                            \
            const float gz = sigm(zA);                                            \
            const float gn = tanh_(fmaf(gr, nh, ni));                             \
            const float hn = gn + gz * (hoM - gn);                                \
            hoM = hn;                                                             \
            if (jw) {                                                             \
                if (hiL) sm.h1[(PAR) ^ 1][nb][j] = (_Float16)hn;                  \
                else     sm.h2[(PAR) ^ 1][n][j]  = (_Float16)hn;                  \
            }                                                                     \
        } else {                                   /* step 0: L1 only */          \
            const f32x4 a = dot2(a1, b10, b11, b1v);                              \
            const float gr = sigm(a.x);                                           \
            const float gz = sigm(a.y);                                           \
            const float gn = tanh_(fmaf(gr, a.z, a.w));                           \
            const float hn = gn - gz * gn;         /* h1o = 0 */                  \
            if (hiL) {                                                            \
                hoM = hn;                                                         \
                if (jw) sm.h1[(PAR) ^ 1][nb][j] = (_Float16)hn;                   \
            }                                                                     \
        }                                                                         \
    } else if (w == 14) {                                                         \
        if (DORED) REDH(PAR, i_ - 2, false, 0)                                    \
    } else if (doX && (i_ + 1) < TSEQ) {                                          \
        if ((XC) == 0) cn = nx;                                                   \
        const float xv_ = ((XC) == 0) ? cn.x : ((XC) == 1) ? cn.y                 \
                        : ((XC) == 2) ? cn.z : cn.w;                              \
        sm.h1[(PAR) ^ 1][bs][XSL] = (_Float16)xv_;                                \
        if ((XC) == 0 && (i_ + 5) < TSEQ) nx = *(const float4*)(xrow + i_ + 5);   \
    }                                                                             \
    BARR();                                                                       \
}

    // ========== MAIN LOOP: 1 barrier/step, unroll-4 (static x-component) ==========
    STEP(0, 0, 1, false, false)
    STEP(1, 1, 2, true,  false)
    for (int i = 2; i < TSEQ - 2; i += 4) {
        STEP(i,     0, 3, true, true)
        STEP(i + 1, 1, 0, true, true)
        STEP(i + 2, 0, 1, true, true)
        STEP(i + 3, 1, 2, true, true)
    }
    STEP(TSEQ - 2, 0, 3, true, true)
    STEP(TSEQ - 1, 1, 0, true, true)

    // ---- unpack lane-packed state for epilogue/future loop (one shfl, once) ----
    float h1o = __shfl_xor(hoM, 8);
    float h2o = hoM;

    // ========== EPILOGUE: h2(TSEQ-1), flush o(TSEQ-2) and o(TSEQ-1) ==========
    // state: h1(TSEQ-1) in h1[0], h2(TSEQ-2) in h2[0]
    if (doM) {
        const half8 b10 = *(const half8*)&sm.h1[0][nb][q * 8];
        const half8 b11 = *(const half8*)&sm.h1[0][nb][32 + q * 8];
        const half8 b20 = *(const half8*)&sm.h2[0][nb][q * 8];
        const half8 b21 = *(const half8*)&sm.h2[0][nb][32 + q * 8];
        const f32x4 g  = dot2(a2, b20, b21, ib2v);
        const f32x4 gi = dot2(a3, b10, b11, ic2v);
        const f32x4 s  = g + gi;
        const float gr = sigm(s.x);
        const float gz = sigm(s.y);
        const float gn = tanh_(fmaf(gr, s.z, s.w));
        const float hn = gn + gz * (h2o - gn);
        h2o = hn;
        if (jv) sm.h2[1][n][j] = (_Float16)hn;
    } else if (w == 14) {
        REDH(0, TSEQ - 2, false, 0)
    }
    BARR();
    if (w == 14) {
        REDH(1, TSEQ - 1, true, 0)      // o(TSEQ-1) -> out + h1[0] x-slot (future x)
    }
    BARR();

    // ========== FUTURE LOOP: serial feedback, 3 barriers/step ==========
    // L1 is IDENTICAL to the main loop (x = o rides slot 51 of h1).
    int fp1 = 0, fh2 = 1;    // h1(TSEQ-1)+o in h1[0], h2(TSEQ-1) in h2[1]
    for (int ts = TSEQ; ts < TT; ++ts) {
        float g2r, g2z, g2n;
        if (doM) {
            const half8 b10 = *(const half8*)&sm.h1[fp1][nb][q * 8];
            const half8 b11 = *(const half8*)&sm.h1[fp1][nb][32 + q * 8];
            const half8 b20 = *(const half8*)&sm.h2[fh2][nb][q * 8];
            const half8 b21 = *(const half8*)&sm.h2[fh2][nb][32 + q * 8];
            {
                const f32x4 g = dot2(a2, b20, b21, ib2v);
                g2r = g.x; g2z = g.y; g2n = g.z;
            }
            {
                const f32x4 a = dot2(a1, b10, b11, b1v);   // x-term via k=51
                const float gr = sigm(a.x);
                const float gz = sigm(a.y);
                const float gn = tanh_(fmaf(gr, a.z, a.w));
                const float hn = gn + gz * (h1o - gn);
                h1o = hn;
                if (jv) sm.h1[fp1 ^ 1][n][j] = (_Float16)hn;
            }
        }
        BARR();
        if (doM) {
            const half8 c0 = *(const half8*)&sm.h1[fp1 ^ 1][nb][q * 8];
            const half8 c1 = *(const half8*)&sm.h1[fp1 ^ 1][nb][32 + q * 8];
            const f32x4 gi = dot2(a3, c0, c1, ic2v);       // n-part lands in .w
            const float gr = sigm(gi.x + g2r);
            const float gz = sigm(gi.y + g2z);
            const float gn = tanh_(fmaf(gr, g2n, gi.w));
            const float hn = gn + gz * (h2o - gn);
            h2o = hn;
            if (jv) sm.h2[fh2 ^ 1][n][j] = (_Float16)hn;
        }
        BARR();
        if (w == 14) {
            REDH(fh2 ^ 1, ts, true, fp1 ^ 1)   // o(ts) -> out + next step's x-slot
        }
        BARR();
        fp1 ^= 1; fh2 ^= 1;
    }
}

extern "C" void kernel_launch(void* const* d_in, const int* in_sizes, int n_in,
                              void* d_out, int out_size, void* d_ws, size_t ws_size,
                              hipStream_t stream) {
    (void)in_sizes; (void)n_in; (void)d_ws; (void)ws_size; (void)out_size;
    gru_persist<<<BB / NB, NT, 0, stream>>>(
        (const float*)d_in[0], (const int*)d_in[1],
        (const float*)d_in[2], (const float*)d_in[3], (const float*)d_in[4], (const float*)d_in[5],
        (const float*)d_in[6], (const float*)d_in[7], (const float*)d_in[8], (const float*)d_in[9],
        (const float*)d_in[10], (const float*)d_in[11],
        (float*)d_out);
}

// Round 15
// 610.661 us; speedup vs baseline: 1.9210x; 1.0833x over previous
//
#include <hip/hip_runtime.h>

#define H    51
#define BB   2048
#define TSEQ 1024
#define NB   8
#define NT   1024       // 16 waves, 4/SIMD
#define KP   72         // f16 h-row stride (144B, 16B-aligned)
#define XSL  51         // x (layer-1 input) lives in k-slot 51 of the h1 buffer
#define L2E  1.4426950408889634f

typedef __attribute__((ext_vector_type(8))) _Float16 half8;
typedef __attribute__((ext_vector_type(4))) float f32x4;

// v_rcp_f32 (1 ulp) via compiler-known intrinsic (proven r3)
__device__ __forceinline__ float rcp_(float x) { return __builtin_amdgcn_rcpf(x); }

// native 2^x. Builtin keeps hazard handling with the compiler (r2's failure
// was NOT the asm exp: re-audit found the real bug was the slot-keyed scale
// select - wih2's n-row lives at slot 3, so keying sc on c==2 mis-scaled it.
// Fixed below by keying on gate g, not slot c.)
#if __has_builtin(__builtin_amdgcn_exp2f)
__device__ __forceinline__ float exp2_(float x) { return __builtin_amdgcn_exp2f(x); }
#else
__device__ __forceinline__ float exp2_(float x) { return exp2f(x); }
#endif

// gate args arrive PRE-SCALED via weights/biases:
//   r,z rows scaled by -log2e:  sigm(x) = 1/(1+2^y),      y = -L2E*x
//   n   rows scaled by 2*log2e: tanh(u) = 1 - 2/(2^y+1),  y = 2*L2E*u
__device__ __forceinline__ float sigm2(float y) { return rcp_(1.0f + exp2_(y)); }
__device__ __forceinline__ float tanh2(float y) { return fmaf(-2.0f, rcp_(exp2_(y) + 1.0f), 1.0f); }

#define MFMA(a, b, c) __builtin_amdgcn_mfma_f32_16x16x32_f16((a), (b), (c), 0, 0, 0)

// lgkmcnt-only barrier (proven r3/r4): LDS ordering without draining vmcnt.
#define BARR() do { asm volatile("s_waitcnt lgkmcnt(0)" ::: "memory");            \
                    __builtin_amdgcn_s_barrier(); } while (0)

struct SM {
    alignas(16) _Float16 h1[2][8][KP];    // parity-buffered h1 (f16); k=51 carries x
    alignas(16) _Float16 h2[2][8][KP];    // parity-buffered h2 (k>=51 stays 0)
};

// A-frags (f16) for tile T of gate-stacked [3H][H] matrix, 4-padded rows:
// padded row 16T+n -> element j=4T+(n>>2), gate slot c=n&3.
// nslot selects which slot carries the n-gate row (2 = normal; 3 = moved).
// PRE-SCALE keyed on GATE g (not slot c - the r2 bug): r,z gates x(-L2E),
// n gate x(2*L2E).
__device__ __forceinline__ void loadA(const float* __restrict__ src, int T, int n, int q,
                                      half8* a, int nslot) {
    const int jt = 4 * T + (n >> 2);
    const int c  = n & 3;
    const int g  = (c == 0) ? 0 : (c == 1) ? 1 : (c == nslot) ? 2 : -1;
    const bool rv = (g >= 0) && (jt < H);
    const float sc = (g == 2) ? (2.0f * L2E) : (-L2E);
#pragma unroll
    for (int kb = 0; kb < 2; ++kb) {
        half8 hv;
#pragma unroll
        for (int jj = 0; jj < 8; ++jj) {
            const int k = kb * 32 + q * 8 + jj;
            const float v = (rv && k < H) ? src[(g * H + jt) * H + k] * sc : 0.f;
            hv[jj] = (_Float16)v;     // RNE
        }
        a[kb] = hv;
    }
}

// L1 A-frag: whh1 rows for k<51 PLUS wih1 column at k==XSL (x rides the MFMA):
// slot c0: [whh1_r | w1r@51]x(-L2E), c1: z likewise, c2: [whh1_n | 0]x(2L2E),
// c3: [0 | w1n@51]x(2L2E)  ->  a.w accumulates 2L2E*(bih1n + w1n*x).
// Scale keyed per slot is CORRECT here: c2 and c3 are both n-gate rows.
__device__ __forceinline__ void loadA1(const float* __restrict__ whh1,
                                       const float* __restrict__ wih1,
                                       int T, int n, int q, half8* a) {
    const int jt = 4 * T + (n >> 2);
    const int c  = n & 3;
    const bool jok = (jt < H);
    const float sc = (c >= 2) ? (2.0f * L2E) : (-L2E);
#pragma unroll
    for (int kb = 0; kb < 2; ++kb) {
        half8 hv;
#pragma unroll
        for (int jj = 0; jj < 8; ++jj) {
            const int k = kb * 32 + q * 8 + jj;
            float v = 0.f;
            if (jok) {
                if (c < 2) {
                    if (k < H)        v = whh1[(c * H + jt) * H + k];
                    else if (k == XSL) v = wih1[c * H + jt];
                } else if (c == 2) {
                    if (k < H)        v = whh1[(2 * H + jt) * H + k];
                } else {              // c == 3: x-only row for the n gate
                    if (k == XSL)     v = wih1[2 * H + jt];
                }
            }
            hv[jj] = (_Float16)(v * sc);
        }
        a[kb] = hv;
    }
}

// chained 2-MFMA matvec over K=64, bias folded into accumulator init
__device__ __forceinline__ f32x4 dot2(const half8* a, half8 b0, half8 b1, f32x4 init) {
    f32x4 acc = init;
    acc = MFMA(a[0], b0, acc);
    acc = MFMA(a[1], b1, acc);
    return acc;
}

__global__ __launch_bounds__(NT, 1) void gru_persist(
    const float* __restrict__ inp, const int* __restrict__ fut,
    const float* __restrict__ wih1, const float* __restrict__ whh1,
    const float* __restrict__ bih1, const float* __restrict__ bhh1,
    const float* __restrict__ wih2, const float* __restrict__ whh2,
    const float* __restrict__ bih2, const float* __restrict__ bhh2,
    const float* __restrict__ wlin, const float* __restrict__ blin,
    float* __restrict__ out)
{
    __shared__ SM sm;
    const int t = threadIdx.x, bg = blockIdx.x;
    const int w = t >> 6, lane = t & 63;
    const int n = lane & 15, q = lane >> 4;
    const int nb = n & 7;                      // broadcast row (n and n+8 share)
    const bool hiL = (n >= 8);                 // lane-pack: hi half runs L1 gates
    // SIMD balance (proven r4): tile 12 on wave 15 -> light waves {12,13,14,15}
    // land on distinct SIMDs; every SIMD carries 3 matvec + 1 light wave.
    const bool doM = (w < 12) || (w == 15);
    const int  T   = (w == 15) ? 12 : (doM ? w : 0);
    const int  j   = 4 * T + q;
    const bool jv  = doM && (j < H) && (n < NB);   // lo-lane write gate
    const bool jw  = doM && (j < H);               // any-lane write gate
    const int  jcl = (j < H) ? j : 0;

    // ---- A-fragments: 6 half8 = 24 VGPRs (wih2's n-row in slot 3) ----
    half8 a1[2], a2[2], a3[2];
    loadA1(whh1, wih1, T, n, q, a1);
    loadA(whh2, T, n, q, a2, 2);
    loadA(wih2, T, n, q, a3, 3);

    // ---- biases folded into accumulator inits, PRE-SCALED (see sigm2/tanh2) ----
    // L1: .x/.y = both r/z biases x(-L2E), .z = bhh1n x(2L2E), .w = bih1n x(2L2E)
    const f32x4 b1v  = {-L2E * (bhh1[jcl] + bih1[jcl]),
                        -L2E * (bhh1[H + jcl] + bih1[H + jcl]),
                        2.f * L2E * bhh1[2 * H + jcl], 2.f * L2E * bih1[2 * H + jcl]};
    // L2 combined chain (whh2 then wih2): proven r4, scaled likewise
    const f32x4 b2c2 = {-L2E * (bhh2[jcl] + bih2[jcl]),
                        -L2E * (bhh2[H + jcl] + bih2[H + jcl]),
                        2.f * L2E * bhh2[2 * H + jcl], 2.f * L2E * bih2[2 * H + jcl]};
    // future-loop split inits (phases separated by a barrier there)
    const f32x4 ib2v = {-L2E * bhh2[jcl], -L2E * bhh2[H + jcl],
                        2.f * L2E * bhh2[2 * H + jcl], 0.f};
    const f32x4 ic2v = {-L2E * bih2[jcl], -L2E * bih2[H + jcl], 0.f,
                        2.f * L2E * bih2[2 * H + jcl]};
    const float blin_r = blin[0];

    // ---- reducer constants (wave 14): lane = n8*8+c8 covers batch x k-chunk ----
    const int n8 = lane >> 3, c8 = lane & 7;
    float wlv[8];
#pragma unroll
    for (int jj = 0; jj < 8; ++jj) {
        const int ix = c8 * 8 + jj;
        wlv[jj] = (ix < H) ? wlin[ix] : 0.f;
    }

    // ---- LDS init (zeros; x/o slots written after the fence) ----
    for (int i = t; i < 2 * 8 * KP; i += NT) { ((short*)sm.h1)[i] = 0; ((short*)sm.h2)[i] = 0; }
    __syncthreads();

    // ---- x staging: wave 13, lanes 0..7 write x(i+1) -> h1[PAR^1][bs][XSL] ----
    // x stored RAW (unscaled): the scaling rides the a1 column at k=51.
    const bool doX = (w == 13) && (lane < 8);
    const int  bs  = lane;
    const float* xrow = inp + (size_t)(bg * NB + (doX ? bs : 0)) * TSEQ;
    float4 cn = make_float4(0.f, 0.f, 0.f, 0.f);
    float4 nx = make_float4(0.f, 0.f, 0.f, 0.f);
    if (doX) {
        cn = *(const float4*)xrow;                 // x[0..3]
        nx = *(const float4*)(xrow + 4);           // x[4..7]
        sm.h1[0][bs][XSL] = (_Float16)cn.x;        // x(0)
    }

    // lane-packed hidden state: lanes n<8 hold h2o, lanes n>=8 hold h1o
    float hoM = 0.f;
    const int TT = TSEQ + fut[0];
    float* outp = out + (size_t)(bg * NB) * (size_t)TT;
    __syncthreads();

// reducer: o = wlin . h2[PARI] + b via ONE ds_read_b128 (h2 holds TRUE values)
#define REDH(PARI, TIDX, DOWR, WRP)                                               \
{                                                                                 \
    const half8 hv = *(const half8*)&sm.h2[PARI][n8][c8 * 8];                     \
    float v = 0.f;                                                                \
    _Pragma("unroll")                                                             \
    for (int jj = 0; jj < 8; ++jj) v = fmaf((float)hv[jj], wlv[jj], v);           \
    v += __shfl_xor(v, 1);                                                        \
    v += __shfl_xor(v, 2);                                                        \
    v += __shfl_xor(v, 4);                                                        \
    if (c8 == 0) {                                                                \
        const float o_ = v + blin_r;                                              \
        if (DOWR) sm.h1[WRP][n8][XSL] = (_Float16)o_;                             \
        outp[(size_t)n8 * TT + (TIDX)] = o_;                                      \
    }                                                                             \
}

// Lane-packed step (proven r11): lanes n<8 run the L2 gate chain, lanes n>=8
// run L1's (MFMA outputs are lane-duplicated via broadcast B); hi lanes write
// h1[n-8][j] directly, lo lanes write h2[n][j]. Gate args pre-scaled -> bare
// exp2 in sigm2/tanh2 (no negate/mul on the TRANS chain).
#define STEP(IV, PAR, XC, DOL2, DORED)                                            \
{                                                                                 \
    const int i_ = (IV);                                                          \
    if (doM) {                                                                    \
        const half8 b10 = *(const half8*)&sm.h1[PAR][nb][q * 8];                  \
        const half8 b11 = *(const half8*)&sm.h1[PAR][nb][32 + q * 8];             \
        if (DOL2) {                                                               \
            const half8 b20 = *(const half8*)&sm.h2[PAR][nb][q * 8];              \
            const half8 b21 = *(const half8*)&sm.h2[PAR][nb][32 + q * 8];         \
            f32x4 g = dot2(a2, b20, b21, b2c2);                                   \
            g = dot2(a3, b10, b11, g);                                            \
            const f32x4 a = dot2(a1, b10, b11, b1v);   /* x-term via k=51 */      \
            const float rA = hiL ? a.x : g.x;                                     \
            const float zA = hiL ? a.y : g.y;                                     \
            const float nh = hiL ? a.z : g.z;                                     \
            const float ni = hiL ? a.w : g.w;                                     \
            const float gr = sigm2(rA);                                           \
            const float gz = sigm2(zA);                                           \
            const float gn = tanh2(fmaf(gr, nh, ni));                             \
            const float hn = gn + gz * (hoM - gn);                                \
            hoM = hn;                                                             \
            if (jw) {                                                             \
                if (hiL) sm.h1[(PAR) ^ 1][nb][j] = (_Float16)hn;                  \
                else     sm.h2[(PAR) ^ 1][n][j]  = (_Float16)hn;                  \
            }                                                                     \
        } else {                                   /* step 0: L1 only */          \
            const f32x4 a = dot2(a1, b10, b11, b1v);                              \
            const float gr = sigm2(a.x);                                          \
            const float gz = sigm2(a.y);                                          \
            const float gn = tanh2(fmaf(gr, a.z, a.w));                           \
            const float hn = gn - gz * gn;         /* h1o = 0 */                  \
            if (hiL) {                                                            \
                hoM = hn;                                                         \
                if (jw) sm.h1[(PAR) ^ 1][nb][j] = (_Float16)hn;                   \
            }                                                                     \
        }                                                                         \
    } else if (w == 14) {                                                         \
        if (DORED) REDH(PAR, i_ - 2, false, 0)                                    \
    } else if (doX && (i_ + 1) < TSEQ) {                                          \
        if ((XC) == 0) cn = nx;                                                   \
        const float xv_ = ((XC) == 0) ? cn.x : ((XC) == 1) ? cn.y                 \
                        : ((XC) == 2) ? cn.z : cn.w;                              \
        sm.h1[(PAR) ^ 1][bs][XSL] = (_Float16)xv_;                                \
        if ((XC) == 0 && (i_ + 5) < TSEQ) nx = *(const float4*)(xrow + i_ + 5);   \
    }                                                                             \
    BARR();                                                                       \
}

    // ========== MAIN LOOP: 1 barrier/step, unroll-4 (static x-component) ==========
    STEP(0, 0, 1, false, false)
    STEP(1, 1, 2, true,  false)
    for (int i = 2; i < TSEQ - 2; i += 4) {
        STEP(i,     0, 3, true, true)
        STEP(i + 1, 1, 0, true, true)
        STEP(i + 2, 0, 1, true, true)
        STEP(i + 3, 1, 2, true, true)
    }
    STEP(TSEQ - 2, 0, 3, true, true)
    STEP(TSEQ - 1, 1, 0, true, true)

    // ---- unpack lane-packed state for epilogue/future loop (one shfl, once) ----
    float h1o = __shfl_xor(hoM, 8);
    float h2o = hoM;

    // ========== EPILOGUE: h2(TSEQ-1), flush o(TSEQ-2) and o(TSEQ-1) ==========
    // state: h1(TSEQ-1) in h1[0], h2(TSEQ-2) in h2[0]
    if (doM) {
        const half8 b10 = *(const half8*)&sm.h1[0][nb][q * 8];
        const half8 b11 = *(const half8*)&sm.h1[0][nb][32 + q * 8];
        const half8 b20 = *(const half8*)&sm.h2[0][nb][q * 8];
        const half8 b21 = *(const half8*)&sm.h2[0][nb][32 + q * 8];
        f32x4 g = dot2(a2, b20, b21, b2c2);
        g = dot2(a3, b10, b11, g);
        const float gr = sigm2(g.x);
        const float gz = sigm2(g.y);
        const float gn = tanh2(fmaf(gr, g.z, g.w));
        const float hn = gn + gz * (h2o - gn);
        h2o = hn;
        if (jv) sm.h2[1][n][j] = (_Float16)hn;
    } else if (w == 14) {
        REDH(0, TSEQ - 2, false, 0)
    }
    BARR();
    if (w == 14) {
        REDH(1, TSEQ - 1, true, 0)      // o(TSEQ-1) -> out + h1[0] x-slot (future x)
    }
    BARR();

    // ========== FUTURE LOOP: serial feedback, 3 barriers/step ==========
    // L1 is IDENTICAL to the main loop (x = o rides slot 51 of h1).
    int fp1 = 0, fh2 = 1;    // h1(TSEQ-1)+o in h1[0], h2(TSEQ-1) in h2[1]
    for (int ts = TSEQ; ts < TT; ++ts) {
        float g2r, g2z, g2n;
        if (doM) {
            const half8 b10 = *(const half8*)&sm.h1[fp1][nb][q * 8];
            const half8 b11 = *(const half8*)&sm.h1[fp1][nb][32 + q * 8];
            const half8 b20 = *(const half8*)&sm.h2[fh2][nb][q * 8];
            const half8 b21 = *(const half8*)&sm.h2[fh2][nb][32 + q * 8];
            {
                const f32x4 g = dot2(a2, b20, b21, ib2v);
                g2r = g.x; g2z = g.y; g2n = g.z;
            }
            {
                const f32x4 a = dot2(a1, b10, b11, b1v);   // x-term via k=51
                const float gr = sigm2(a.x);
                const float gz = sigm2(a.y);
                const float gn = tanh2(fmaf(gr, a.z, a.w));
                const float hn = gn + gz * (h1o - gn);
                h1o = hn;
                if (jv) sm.h1[fp1 ^ 1][n][j] = (_Float16)hn;
            }
        }
        BARR();
        if (doM) {
            const half8 c0 = *(const half8*)&sm.h1[fp1 ^ 1][nb][q * 8];
            const half8 c1 = *(const half8*)&sm.h1[fp1 ^ 1][nb][32 + q * 8];
            const f32x4 gi = dot2(a3, c0, c1, ic2v);       // n-part lands in .w
            const float gr = sigm2(gi.x + g2r);
            const float gz = sigm2(gi.y + g2z);
            const float gn = tanh2(fmaf(gr, g2n, gi.w));
            const float hn = gn + gz * (h2o - gn);
            h2o = hn;
            if (jv) sm.h2[fh2 ^ 1][n][j] = (_Float16)hn;
        }
        BARR();
        if (w == 14) {
            REDH(fh2 ^ 1, ts, true, fp1 ^ 1)   // o(ts) -> out + next step's x-slot
        }
        BARR();
        fp1 ^= 1; fh2 ^= 1;
    }
}

extern "C" void kernel_launch(void* const* d_in, const int* in_sizes, int n_in,
                              void* d_out, int out_size, void* d_ws, size_t ws_size,
                              hipStream_t stream) {
    (void)in_sizes; (void)n_in; (void)d_ws; (void)ws_size; (void)out_size;
    gru_persist<<<BB / NB, NT, 0, stream>>>(
        (const float*)d_in[0], (const int*)d_in[1],
        (const float*)d_in[2], (const float*)d_in[3], (const float*)d_in[4], (const float*)d_in[5],
        (const float*)d_in[6], (const float*)d_in[7], (const float*)d_in[8], (const float*)d_in[9],
        (const float*)d_in[10], (const float*)d_in[11],
        (float*)d_out);
}